// Round 1
// baseline (194.610 us; speedup 1.0000x reference)
//
#include <hip/hip_runtime.h>
#include <cfloat>

namespace {
constexpr int H = 256;
constexpr int A = 4096;
constexpr int B = 32;
constexpr int G = 512;
constexpr int K = 16;
constexpr size_t SLICE = (size_t)A * H;   // elements per batch slice = 1,048,576
}

static __device__ __forceinline__ float4 f4max(float4 a, float4 b) {
    float4 r;
    r.x = fmaxf(a.x, b.x);
    r.y = fmaxf(a.y, b.y);
    r.z = fmaxf(a.z, b.z);
    r.w = fmaxf(a.w, b.w);
    return r;
}

// Phase 1: rowmax[a*H + h] = max_b x[b*SLICE + a*H + h]
// Grid: (A*H/4)/256 = 1024 blocks x 256 threads; each thread owns one float4.
// A wave's 64 lanes cover exactly one 256-float row slice -> every load is a
// fully coalesced contiguous 1 KiB transaction. Pure HBM streaming.
__global__ __launch_bounds__(256) void rowmax_kernel(const float* __restrict__ x,
                                                     float* __restrict__ rowmax) {
    const int t  = blockIdx.x * 256 + threadIdx.x;   // 0 .. A*H/4 - 1
    const size_t off = (size_t)t << 2;               // element offset into one slice
    const float* p = x + off;

    // two accumulators to shorten the fmax dependency chain
    float4 m0 = *(const float4*)p;
    float4 m1 = *(const float4*)(p + SLICE);
#pragma unroll
    for (int b = 2; b < B; b += 2) {
        float4 v0 = *(const float4*)(p + (size_t)b * SLICE);
        float4 v1 = *(const float4*)(p + (size_t)(b + 1) * SLICE);
        m0 = f4max(m0, v0);
        m1 = f4max(m1, v1);
    }
    *(float4*)(rowmax + off) = f4max(m0, m1);
}

// Phase 2: out[g*H + h] = max_k rowmax[idx[g*K+k]*H + h]
// Grid: G blocks x 64 threads; lane i owns float4 at h = 4*i.
// rowmax is 4 MiB -> lives in L2/L3; this kernel is ~1-2 us.
__global__ __launch_bounds__(64) void gather_kernel(const float* __restrict__ rowmax,
                                                    const int* __restrict__ idx,
                                                    float* __restrict__ out) {
    const int g  = blockIdx.x;
    const int h4 = threadIdx.x << 2;

    float4 m = make_float4(-FLT_MAX, -FLT_MAX, -FLT_MAX, -FLT_MAX);
#pragma unroll
    for (int k = 0; k < K; ++k) {
        const int r = idx[g * K + k];                 // wave-uniform load
        float4 v = *(const float4*)(rowmax + (size_t)r * H + h4);
        m = f4max(m, v);
    }
    *(float4*)(out + (size_t)g * H + h4) = m;
}

// Fallback (no workspace needed): fused gather-max.
// Grid: G blocks x 256 threads. Wave w handles batches [8w, 8w+8); lane = h/4.
__global__ __launch_bounds__(256) void fused_kernel(const float* __restrict__ x,
                                                    const int* __restrict__ idx,
                                                    float* __restrict__ out) {
    const int g    = blockIdx.x;
    const int lane = threadIdx.x & 63;
    const int wave = threadIdx.x >> 6;
    const int h4   = lane << 2;
    const int b0   = wave * 8;

    float4 m0 = make_float4(-FLT_MAX, -FLT_MAX, -FLT_MAX, -FLT_MAX);
    float4 m1 = m0;

    for (int k = 0; k < K; ++k) {
        const int r = idx[g * K + k];
        const float* p = x + (size_t)b0 * SLICE + (size_t)r * H + h4;
#pragma unroll
        for (int b = 0; b < 8; b += 2) {
            float4 v0 = *(const float4*)(p + (size_t)b * SLICE);
            float4 v1 = *(const float4*)(p + (size_t)(b + 1) * SLICE);
            m0 = f4max(m0, v0);
            m1 = f4max(m1, v1);
        }
    }
    float4 m = f4max(m0, m1);

    __shared__ float4 part[4][64];
    part[wave][lane] = m;
    __syncthreads();
    if (wave == 0) {
        float4 r = f4max(f4max(part[0][lane], part[1][lane]),
                         f4max(part[2][lane], part[3][lane]));
        *(float4*)(out + (size_t)g * H + h4) = r;
    }
}

extern "C" void kernel_launch(void* const* d_in, const int* in_sizes, int n_in,
                              void* d_out, int out_size, void* d_ws, size_t ws_size,
                              hipStream_t stream) {
    const float* x   = (const float*)d_in[0];
    const int*   idx = (const int*)d_in[1];
    float*       out = (float*)d_out;

    const size_t rowmax_bytes = (size_t)A * H * sizeof(float);  // 4 MiB
    if (ws_size >= rowmax_bytes) {
        float* rowmax = (float*)d_ws;
        rowmax_kernel<<<(A * H / 4) / 256, 256, 0, stream>>>(x, rowmax);
        gather_kernel<<<G, 64, 0, stream>>>(rowmax, idx, out);
    } else {
        fused_kernel<<<G, 256, 0, stream>>>(x, idx, out);
    }
}